// Round 1
// baseline (56.102 us; speedup 1.0000x reference)
//
#include <hip/hip_runtime.h>

#define IMG_SIZE 480
#define OUT_HW   224
#define BATCH    128
#define CHAN     3
#define XQ       (OUT_HW / 4)   // 56 groups of 4 output x per thread

__global__ __launch_bounds__(256) void crop_resize_kernel(
    const float* __restrict__ img,   // [B, 3, 480, 480]
    const float* __restrict__ box,   // [B, 4] normalized cxcywh
    float* __restrict__ out)         // [B, 3*224*224]
{
    int idx = blockIdx.x * blockDim.x + threadIdx.x;
    // idx -> (b, c, y, x4)
    int x4 = idx % XQ;
    int t  = idx / XQ;
    int y  = t % OUT_HW;
    t /= OUT_HW;
    int c  = t % CHAN;
    int b  = t / CHAN;
    if (b >= BATCH) return;

    // ---- box math (matches reference: *480, cxcywh->xyxy, trunc->int) ----
    const float4 bx = *reinterpret_cast<const float4*>(box + (size_t)b * 4);
    float fcx = bx.x * (float)IMG_SIZE;
    float fcy = bx.y * (float)IMG_SIZE;
    float fw  = bx.z * (float)IMG_SIZE;
    float fh  = bx.w * (float)IMG_SIZE;
    int xa = (int)truncf(fcx - 0.5f * fw);
    int ya = (int)truncf(fcy - 0.5f * fh);
    int xb = (int)truncf(fcx + 0.5f * fw);
    int yb = (int)truncf(fcy + 0.5f * fh);
    float ch = (float)(yb - ya);
    float cw = (float)(xb - xa);

    // ---- vertical source coordinate (shared across the 4 pixels) ----
    float sy = ((float)y + 0.5f) * ch / (float)OUT_HW - 0.5f;
    sy = fminf(fmaxf(sy, 0.0f), ch - 1.0f);
    int   y0 = (int)floorf(sy);
    float wy = sy - (float)y0;
    int   y1 = min(y0 + 1, yb - ya - 1);

    const float* __restrict__ plane = img + ((size_t)b * CHAN + c) * (IMG_SIZE * IMG_SIZE);
    const float* __restrict__ row0  = plane + (size_t)(ya + y0) * IMG_SIZE;
    const float* __restrict__ row1  = plane + (size_t)(ya + y1) * IMG_SIZE;

    float res[4];
    #pragma unroll
    for (int i = 0; i < 4; ++i) {
        int x = x4 * 4 + i;
        float sx = ((float)x + 0.5f) * cw / (float)OUT_HW - 0.5f;
        sx = fminf(fmaxf(sx, 0.0f), cw - 1.0f);
        int   x0 = (int)floorf(sx);
        float wx = sx - (float)x0;
        int   x1 = min(x0 + 1, xb - xa - 1);

        float t0 = row0[xa + x0];
        float t1 = row0[xa + x1];
        float u0 = row1[xa + x0];
        float u1 = row1[xa + x1];

        float top = t0 * (1.0f - wx) + t1 * wx;
        float bot = u0 * (1.0f - wx) + u1 * wx;
        res[i]    = top * (1.0f - wy) + bot * wy;
    }

    size_t oidx = (((size_t)b * CHAN + c) * OUT_HW + y) * OUT_HW + (size_t)x4 * 4;
    float4 v = make_float4(res[0], res[1], res[2], res[3]);
    *reinterpret_cast<float4*>(out + oidx) = v;
}

extern "C" void kernel_launch(void* const* d_in, const int* in_sizes, int n_in,
                              void* d_out, int out_size, void* d_ws, size_t ws_size,
                              hipStream_t stream) {
    const float* img = (const float*)d_in[0];
    const float* box = (const float*)d_in[1];
    float* out = (float*)d_out;

    const int total_threads = BATCH * CHAN * OUT_HW * XQ;  // 4,816,896
    const int block = 256;
    const int grid  = (total_threads + block - 1) / block; // 18,816
    crop_resize_kernel<<<grid, block, 0, stream>>>(img, box, out);
}

// Round 2
// 32.290 us; speedup vs baseline: 1.7374x; 1.7374x over previous
//
#include <hip/hip_runtime.h>

#define IMG   480
#define OUT   224
#define BATCH 128
#define CHAN  3
#define YT    28            // output rows per block tile
#define NTILE (OUT / YT)    // 8 tiles per (b,c) plane
#define NROW  32            // max source rows needed: 27*240/224 + 2 < 31
#define NCOL  248           // max source cols needed: cw(<=240) + align(3) -> 244, pad to 248

__global__ __launch_bounds__(256) void crop_resize_kernel(
    const float* __restrict__ img,   // [B, 3, 480, 480]
    const float* __restrict__ box,   // [B, 4] normalized cxcywh
    float* __restrict__ out)         // [B, 3*224*224]
{
    __shared__ float lds[NROW * NCOL];   // 31.75 KB

    const int bid = blockIdx.x;
    const int yt  = bid % NTILE;
    const int bc  = bid / NTILE;         // b*3 + c
    const int b   = bc / CHAN;

    // ---- block-uniform box math (matches reference exactly) ----
    const float fcx = box[b * 4 + 0] * (float)IMG;
    const float fcy = box[b * 4 + 1] * (float)IMG;
    const float fw  = box[b * 4 + 2] * (float)IMG;
    const float fh  = box[b * 4 + 3] * (float)IMG;
    const int xa = (int)truncf(fcx - 0.5f * fw);
    const int ya = (int)truncf(fcy - 0.5f * fh);
    const int xb = (int)truncf(fcx + 0.5f * fw);
    const int yb = (int)truncf(fcy + 0.5f * fh);
    const int icw = xb - xa, ich = yb - ya;
    const float cw = (float)icw, ch = (float)ich;

    const float inv_out = 1.0f / (float)OUT;   // compile-time exact
    const float sch = ch * inv_out;
    const float scw = cw * inv_out;

    const int ybase = yt * YT;

    // ---- source row range for this tile ----
    float sy_first = fminf(fmaxf(((float)ybase + 0.5f) * sch - 0.5f, 0.0f), ch - 1.0f);
    float sy_last  = fminf(fmaxf(((float)(ybase + YT - 1) + 0.5f) * sch - 0.5f, 0.0f), ch - 1.0f);
    const int r_lo = (int)floorf(sy_first);
    const int r_hi = min((int)floorf(sy_last) + 1, ich - 1);
    const int nr   = r_hi - r_lo + 1;          // <= 31

    // ---- source col window, aligned to float4 ----
    const int cb  = xa & ~3;                   // aligned global col base
    const int dx  = xa - cb;                   // 0..3
    const int nw4 = (dx + icw + 3) >> 2;       // float4s per row, <= 61

    const float* __restrict__ plane = img + (size_t)bc * (IMG * IMG);

    // ---- stage source window into LDS with dense float4 loads ----
    const int lane = threadIdx.x & 63;
    const int wv   = threadIdx.x >> 6;
    for (int r = wv; r < nr; r += 4) {
        const float4* __restrict__ src =
            reinterpret_cast<const float4*>(plane + (size_t)(ya + r_lo + r) * IMG + cb);
        float4* dst = reinterpret_cast<float4*>(&lds[r * NCOL]);
        for (int q = lane; q < nw4; q += 64)
            dst[q] = src[q];
    }
    __syncthreads();

    // ---- compute 28 x 224 output pixels from LDS ----
    for (int task = threadIdx.x; task < YT * (OUT / 4); task += 256) {
        const int x4 = task % (OUT / 4);
        const int yy = task / (OUT / 4);
        const int y  = ybase + yy;

        float sy = fminf(fmaxf(((float)y + 0.5f) * sch - 0.5f, 0.0f), ch - 1.0f);
        const int   y0 = (int)floorf(sy);
        const float wy = sy - (float)y0;
        const int   y1 = min(y0 + 1, ich - 1);

        const float* __restrict__ r0 = &lds[(y0 - r_lo) * NCOL + dx];
        const float* __restrict__ r1 = &lds[(y1 - r_lo) * NCOL + dx];

        float res[4];
        #pragma unroll
        for (int i = 0; i < 4; ++i) {
            const int x = x4 * 4 + i;
            float sx = fminf(fmaxf(((float)x + 0.5f) * scw - 0.5f, 0.0f), cw - 1.0f);
            const int   x0 = (int)floorf(sx);
            const float wx = sx - (float)x0;
            const int   x1 = min(x0 + 1, icw - 1);

            const float t0 = r0[x0], t1 = r0[x1];
            const float u0 = r1[x0], u1 = r1[x1];
            const float top = t0 * (1.0f - wx) + t1 * wx;
            const float bot = u0 * (1.0f - wx) + u1 * wx;
            res[i] = top * (1.0f - wy) + bot * wy;
        }

        const size_t oidx = (((size_t)bc) * OUT + y) * OUT + (size_t)x4 * 4;
        *reinterpret_cast<float4*>(out + oidx) =
            make_float4(res[0], res[1], res[2], res[3]);
    }
}

extern "C" void kernel_launch(void* const* d_in, const int* in_sizes, int n_in,
                              void* d_out, int out_size, void* d_ws, size_t ws_size,
                              hipStream_t stream) {
    const float* img = (const float*)d_in[0];
    const float* box = (const float*)d_in[1];
    float* out = (float*)d_out;

    const int grid = BATCH * CHAN * NTILE;   // 3072 blocks
    crop_resize_kernel<<<grid, 256, 0, stream>>>(img, box, out);
}

// Round 3
// 31.411 us; speedup vs baseline: 1.7860x; 1.0280x over previous
//
#include <hip/hip_runtime.h>

#define IMG   480
#define OUT   224
#define BATCH 128
#define CHAN  3
#define YT    28            // output rows per block tile
#define NTILE (OUT / YT)    // 8 tiles per (b,c) plane
#define NROW  32            // max source rows needed: 27*240/224 + 2 < 31
#define NCOL  248           // max source cols needed: cw(<=240) + align(3) -> 244, pad to 248
#define XQN   (OUT / 4)     // 56 x-groups; thread i handles x = i, i+56, i+112, i+168

__global__ __launch_bounds__(256) void crop_resize_kernel(
    const float* __restrict__ img,   // [B, 3, 480, 480]
    const float* __restrict__ box,   // [B, 4] normalized cxcywh
    float* __restrict__ out)         // [B, 3*224*224]
{
    __shared__ float lds[NROW * NCOL];   // 31.75 KB

    const int bid = blockIdx.x;
    const int yt  = bid % NTILE;
    const int bc  = bid / NTILE;         // b*3 + c
    const int b   = bc / CHAN;

    // ---- block-uniform box math (matches reference exactly) ----
    const float fcx = box[b * 4 + 0] * (float)IMG;
    const float fcy = box[b * 4 + 1] * (float)IMG;
    const float fw  = box[b * 4 + 2] * (float)IMG;
    const float fh  = box[b * 4 + 3] * (float)IMG;
    const int xa = (int)truncf(fcx - 0.5f * fw);
    const int ya = (int)truncf(fcy - 0.5f * fh);
    const int xb = (int)truncf(fcx + 0.5f * fw);
    const int yb = (int)truncf(fcy + 0.5f * fh);
    const int icw = xb - xa, ich = yb - ya;
    const float cw = (float)icw, ch = (float)ich;

    const float inv_out = 1.0f / (float)OUT;   // compile-time exact
    const float sch = ch * inv_out;
    const float scw = cw * inv_out;

    const int ybase = yt * YT;

    // ---- source row range for this tile ----
    float sy_first = fminf(fmaxf(((float)ybase + 0.5f) * sch - 0.5f, 0.0f), ch - 1.0f);
    float sy_last  = fminf(fmaxf(((float)(ybase + YT - 1) + 0.5f) * sch - 0.5f, 0.0f), ch - 1.0f);
    const int r_lo = (int)floorf(sy_first);
    const int r_hi = min((int)floorf(sy_last) + 1, ich - 1);
    const int nr   = r_hi - r_lo + 1;          // <= 31

    // ---- source col window, aligned to float4 ----
    const int cb  = xa & ~3;                   // aligned global col base
    const int dx  = xa - cb;                   // 0..3
    const int nw4 = (dx + icw + 3) >> 2;       // float4s per row, <= 61

    const float* __restrict__ plane = img + (size_t)bc * (IMG * IMG);

    // ---- stage source window into LDS with dense float4 loads ----
    const int lane = threadIdx.x & 63;
    const int wv   = threadIdx.x >> 6;
    for (int r = wv; r < nr; r += 4) {
        const float4* __restrict__ src =
            reinterpret_cast<const float4*>(plane + (size_t)(ya + r_lo + r) * IMG + cb);
        float4* dst = reinterpret_cast<float4*>(&lds[r * NCOL]);
        for (int q = lane; q < nw4; q += 64)
            dst[q] = src[q];
    }
    __syncthreads();

    // ---- compute 28 x 224 output pixels from LDS ----
    // thread handles 4 pixels strided by 56 in x: lane-consecutive threads
    // read LDS at stride scw (<1.07 words) -> <=2-way bank aliasing (free).
    for (int task = threadIdx.x; task < YT * XQN; task += 256) {
        const int xq = task % XQN;
        const int yy = task / XQN;
        const int y  = ybase + yy;

        float sy = fminf(fmaxf(((float)y + 0.5f) * sch - 0.5f, 0.0f), ch - 1.0f);
        const int   y0 = (int)floorf(sy);
        const float wy = sy - (float)y0;
        const int   y1 = min(y0 + 1, ich - 1);

        const float* __restrict__ r0 = &lds[(y0 - r_lo) * NCOL + dx];
        const float* __restrict__ r1 = &lds[(y1 - r_lo) * NCOL + dx];

        const size_t obase = (((size_t)bc) * OUT + y) * OUT;

        #pragma unroll
        for (int i = 0; i < 4; ++i) {
            const int x = xq + i * XQN;
            float sx = fminf(fmaxf(((float)x + 0.5f) * scw - 0.5f, 0.0f), cw - 1.0f);
            const int   x0 = (int)floorf(sx);
            const float wx = sx - (float)x0;
            const int   x1 = min(x0 + 1, icw - 1);

            const float t0 = r0[x0], t1 = r0[x1];
            const float u0 = r1[x0], u1 = r1[x1];
            const float top = t0 * (1.0f - wx) + t1 * wx;
            const float bot = u0 * (1.0f - wx) + u1 * wx;
            out[obase + x] = top * (1.0f - wy) + bot * wy;
        }
    }
}

extern "C" void kernel_launch(void* const* d_in, const int* in_sizes, int n_in,
                              void* d_out, int out_size, void* d_ws, size_t ws_size,
                              hipStream_t stream) {
    const float* img = (const float*)d_in[0];
    const float* box = (const float*)d_in[1];
    float* out = (float*)d_out;

    const int grid = BATCH * CHAN * NTILE;   // 3072 blocks
    crop_resize_kernel<<<grid, 256, 0, stream>>>(img, box, out);
}

// Round 4
// 28.936 us; speedup vs baseline: 1.9388x; 1.0856x over previous
//
#include <hip/hip_runtime.h>

#define IMG   480
#define OUT   224
#define BATCH 128
#define CHAN  3
#define YT    16            // output rows per block tile
#define NTILE (OUT / YT)    // 14 tiles per (b,c) plane
#define NCOL  248           // intermediate row: max 244 used floats, 992B (16B-aligned)
#define XQN   56            // thread handles x = xq, xq+56, xq+112, xq+168 (same y)

__global__ __launch_bounds__(256) void crop_resize_kernel(
    const float* __restrict__ img,   // [B, 3, 480, 480]
    const float* __restrict__ box,   // [B, 4] normalized cxcywh
    float* __restrict__ out)         // [B, 3*224*224]
{
    __shared__ float inter[YT * NCOL];   // 15.5 KB: vertically-resized rows

    const int bid = blockIdx.x;
    const int yt  = bid % NTILE;
    const int bc  = bid / NTILE;         // b*3 + c
    const int b   = bc / CHAN;

    // ---- block-uniform box math (matches reference exactly) ----
    const float fcx = box[b * 4 + 0] * (float)IMG;
    const float fcy = box[b * 4 + 1] * (float)IMG;
    const float fw  = box[b * 4 + 2] * (float)IMG;
    const float fh  = box[b * 4 + 3] * (float)IMG;
    const int xa = (int)truncf(fcx - 0.5f * fw);
    const int ya = (int)truncf(fcy - 0.5f * fh);
    const int xb = (int)truncf(fcx + 0.5f * fw);
    const int yb = (int)truncf(fcy + 0.5f * fh);
    const int icw = xb - xa, ich = yb - ya;        // <= 240 each
    const float cw = (float)icw, ch = (float)ich;

    const float inv_out = 1.0f / (float)OUT;
    const float sch = ch * inv_out;
    const float scw = cw * inv_out;

    const int ybase = yt * YT;

    // ---- source col window, aligned to float4 ----
    const int cb  = xa & ~3;                   // aligned global col base
    const int dx  = xa - cb;                   // 0..3
    const int nw4 = (dx + icw + 3) >> 2;       // float4s per row, <= 61 (< 64)

    const float* __restrict__ plane = img + (size_t)bc * (IMG * IMG);

    // ---- pass 1: vertical lerp, global -> LDS (no raw staging) ----
    const int lane = threadIdx.x & 63;
    const int wv   = threadIdx.x >> 6;
    for (int yy = wv; yy < YT; yy += 4) {      // 4 rows per wave
        const int y = ybase + yy;
        float sy = fminf(fmaxf(((float)y + 0.5f) * sch - 0.5f, 0.0f), ch - 1.0f);
        const int   y0 = (int)floorf(sy);
        const float wy = sy - (float)y0;
        const int   y1 = min(y0 + 1, ich - 1);

        const float4* __restrict__ r0 =
            reinterpret_cast<const float4*>(plane + (size_t)(ya + y0) * IMG + cb);
        const float4* __restrict__ r1 =
            reinterpret_cast<const float4*>(plane + (size_t)(ya + y1) * IMG + cb);
        float4* drow = reinterpret_cast<float4*>(&inter[yy * NCOL]);

        if (lane < nw4) {                      // single coalesced sweep per row
            const float4 a = r0[lane];
            const float4 c = r1[lane];
            float4 v;
            v.x = a.x * (1.0f - wy) + c.x * wy;
            v.y = a.y * (1.0f - wy) + c.y * wy;
            v.z = a.z * (1.0f - wy) + c.z * wy;
            v.w = a.w * (1.0f - wy) + c.w * wy;
            drow[lane] = v;
        }
    }
    __syncthreads();

    // ---- pass 2: horizontal lerp, LDS -> out (2 taps per pixel) ----
    for (int task = threadIdx.x; task < YT * XQN; task += 256) {
        const int xq = task % XQN;
        const int yy = task / XQN;
        const float* __restrict__ r = &inter[yy * NCOL + dx];
        const size_t obase = (((size_t)bc) * OUT + (ybase + yy)) * OUT;

        #pragma unroll
        for (int i = 0; i < 4; ++i) {
            const int x = xq + i * XQN;
            float sx = fminf(fmaxf(((float)x + 0.5f) * scw - 0.5f, 0.0f), cw - 1.0f);
            const int   x0 = (int)floorf(sx);
            const float wx = sx - (float)x0;
            const int   x1 = min(x0 + 1, icw - 1);
            out[obase + x] = r[x0] * (1.0f - wx) + r[x1] * wx;
        }
    }
}

extern "C" void kernel_launch(void* const* d_in, const int* in_sizes, int n_in,
                              void* d_out, int out_size, void* d_ws, size_t ws_size,
                              hipStream_t stream) {
    const float* img = (const float*)d_in[0];
    const float* box = (const float*)d_in[1];
    float* out = (float*)d_out;

    const int grid = BATCH * CHAN * NTILE;   // 5376 blocks
    crop_resize_kernel<<<grid, 256, 0, stream>>>(img, box, out);
}